// Round 1
// baseline (451.965 us; speedup 1.0000x reference)
//
#include <hip/hip_runtime.h>
#include <stdint.h>

typedef unsigned long long u64;
typedef unsigned int u32;

constexpr int Ccand = 32;   // candidates per row (setup: C=32)
constexpr int Evoc  = 512;  // vocab size (setup: E=512)
constexpr int Tgt   = 64;   // target_size
constexpr int Nadd  = Tgt - Ccand; // 32 to add

// One wave (64 lanes) per row.
// Lane l owns output columns e in {4l..4l+3} and {256+4l..256+4l+3}.
__global__ __launch_bounds__(256, 1) void cooc_expand(
    const int* __restrict__ cand_ids,
    const float* __restrict__ cand_scores,
    const float* __restrict__ cooc,
    float* __restrict__ out_ids,
    float* __restrict__ out_scores,
    int B)
{
    const int lane = threadIdx.x & 63;
    const int wid  = threadIdx.x >> 6;
    const int row  = blockIdx.x * 4 + wid;
    if (row >= B) return;   // wave-uniform

    // ---- load this row's candidates (lanes 0..31 hold them) ----
    int   my_id = -1;
    float my_s  = 0.0f;
    if (lane < Ccand) {
        my_id = cand_ids[(size_t)row * Ccand + lane];
        my_s  = cand_scores[(size_t)row * Ccand + lane];
    }

    // ---- duplicate merge, exactly np.add.at order (ascending i, from 0.0) ----
    int   first = 64;
    float sm    = 0.0f;
    #pragma unroll
    for (int j = 0; j < Ccand; ++j) {
        int   idj = __shfl(my_id, j);
        float sj  = __shfl(my_s,  j);
        bool match = (idj == my_id);
        if (match && j < first) first = j;
        sm += match ? sj : 0.0f;   // +0.0f is exact for our positive partials
    }
    bool alive = (lane < Ccand) && (first == lane);

    u64 aball = __ballot(alive);
    int m = __popcll(aball);

    // ---- rank alive entries by ascending id (alive ids are distinct) ----
    int rk = 0;
    #pragma unroll
    for (int j = 0; j < Ccand; ++j) {
        int idj = __shfl(my_id, j);
        bool aj = (aball >> j) & 1ull;
        rk += (aj && idj < my_id) ? 1 : 0;
    }
    // alive -> rank in [0,m); dead (l<32) -> l+32; lanes>=32 -> self.
    // Collisions only land in lanes we never read (>= m).
    int dst = alive ? rk : ((lane < 32) ? (lane + 32) : lane);
    int sorted_id = __builtin_amdgcn_ds_permute(dst << 2, my_id);
    int sorted_sb = __builtin_amdgcn_ds_permute(dst << 2, __float_as_int(sm));

    // ---- accumulate: single sequential FMA chain per e, ascending id ----
    // (matches sequential-k f32 sgemm; skipping zero terms is bit-exact)
    float acc[8] = {0.f,0.f,0.f,0.f,0.f,0.f,0.f,0.f};
    u32 maskbits = 0;
    const int l4 = lane << 2;
    for (int t = 0; t < m; ++t) {
        int   e = __shfl(sorted_id, t);
        float s = __int_as_float(__shfl(sorted_sb, t));
        const float* rp = cooc + (size_t)e * Evoc;
        const float4 a = *reinterpret_cast<const float4*>(rp + l4);
        const float4 b = *reinterpret_cast<const float4*>(rp + 256 + l4);
        acc[0] = fmaf(s, a.x, acc[0]);
        acc[1] = fmaf(s, a.y, acc[1]);
        acc[2] = fmaf(s, a.z, acc[2]);
        acc[3] = fmaf(s, a.w, acc[3]);
        acc[4] = fmaf(s, b.x, acc[4]);
        acc[5] = fmaf(s, b.y, acc[5]);
        acc[6] = fmaf(s, b.z, acc[6]);
        acc[7] = fmaf(s, b.w, acc[7]);
        // mark the masked slot (reference sets cooc_scores[b, e] = -inf)
        int owner = (e & 255) >> 2;
        if (owner == lane) maskbits |= 1u << (((e >> 8) << 2) | (e & 3));
    }

    // ---- build u64 sort keys: (float bits << 32) | (511 - e) ----
    // all unmasked values are >= 0 -> raw bits are order-monotone;
    // masked -> 0 in the high half (never reaches top-32: >=480 survivors);
    // low bits give tie-break by ascending e AND make keys globally unique.
    u64 k0, k1, k2, k3, k4, k5, k6, k7;
    {
        u32 v;
        v = __float_as_uint(acc[0]); if (maskbits & 1u)   v = 0u; k0 = ((u64)v << 32) | (u32)(511 - (l4 + 0));
        v = __float_as_uint(acc[1]); if (maskbits & 2u)   v = 0u; k1 = ((u64)v << 32) | (u32)(511 - (l4 + 1));
        v = __float_as_uint(acc[2]); if (maskbits & 4u)   v = 0u; k2 = ((u64)v << 32) | (u32)(511 - (l4 + 2));
        v = __float_as_uint(acc[3]); if (maskbits & 8u)   v = 0u; k3 = ((u64)v << 32) | (u32)(511 - (l4 + 3));
        v = __float_as_uint(acc[4]); if (maskbits & 16u)  v = 0u; k4 = ((u64)v << 32) | (u32)(511 - (256 + l4 + 0));
        v = __float_as_uint(acc[5]); if (maskbits & 32u)  v = 0u; k5 = ((u64)v << 32) | (u32)(511 - (256 + l4 + 1));
        v = __float_as_uint(acc[6]); if (maskbits & 64u)  v = 0u; k6 = ((u64)v << 32) | (u32)(511 - (256 + l4 + 2));
        v = __float_as_uint(acc[7]); if (maskbits & 128u) v = 0u; k7 = ((u64)v << 32) | (u32)(511 - (256 + l4 + 3));
    }

    // ---- per-lane descending sort of 8 keys (Batcher odd-even merge, 19 CE) ----
    #define CE(a,b) { if (a < b) { u64 tt_ = a; a = b; b = tt_; } }
    CE(k0,k1) CE(k2,k3) CE(k4,k5) CE(k6,k7)
    CE(k0,k2) CE(k1,k3) CE(k4,k6) CE(k5,k7)
    CE(k1,k2) CE(k5,k6)
    CE(k0,k4) CE(k1,k5) CE(k2,k6) CE(k3,k7)
    CE(k2,k4) CE(k3,k5)
    CE(k1,k2) CE(k3,k4) CE(k5,k6)
    #undef CE

    // ---- 32 x wave-argmax selection; winner shifts its sorted list ----
    float rec_v = 0.0f;
    int   rec_e = 0;
    for (int t = 0; t < Nadd; ++t) {
        u64 w = k0;
        #pragma unroll
        for (int sft = 1; sft < 64; sft <<= 1) {
            u64 o = __shfl_xor(w, sft);
            w = (o > w) ? o : w;
        }
        bool win = (k0 == w);   // keys globally unique -> exactly one winner
        k0 = win ? k1 : k0;
        k1 = win ? k2 : k1;
        k2 = win ? k3 : k2;
        k3 = win ? k4 : k3;
        k4 = win ? k5 : k4;
        k5 = win ? k6 : k5;
        k6 = win ? k7 : k6;
        k7 = win ? 0ull : k7;
        if (lane == 32 + t) {
            rec_e = 511 - (int)(w & 511ull);
            rec_v = __uint_as_float((u32)(w >> 32));
        }
    }

    // ---- coalesced stores: [orig 32 | selected 32] for ids and scores ----
    const size_t ob = (size_t)row * Tgt;
    float oid, osc;
    if (lane < Ccand) { oid = (float)my_id; osc = my_s; }
    else              { oid = (float)rec_e; osc = rec_v; }
    out_ids[ob + lane]    = oid;
    out_scores[ob + lane] = osc;
}

extern "C" void kernel_launch(void* const* d_in, const int* in_sizes, int n_in,
                              void* d_out, int out_size, void* d_ws, size_t ws_size,
                              hipStream_t stream) {
    const int*   ids    = (const int*)d_in[0];
    const float* scores = (const float*)d_in[1];
    const float* cooc   = (const float*)d_in[2];
    // d_in[3] is target_size (=64); shapes are static for this problem.
    int B = in_sizes[0] / Ccand;
    float* out_ids    = (float*)d_out;
    float* out_scores = out_ids + (size_t)B * Tgt;
    int blocks = (B + 3) / 4;
    hipLaunchKernelGGL(cooc_expand, dim3(blocks), dim3(256), 0, stream,
                       ids, scores, cooc, out_ids, out_scores, B);
}